// Round 7
// baseline (774.281 us; speedup 1.0000x reference)
//
#include <hip/hip_runtime.h>

#define Bv 1024
#define Ev 256
#define Lv 8
#define Rv 10000
#define NP1 10001
#define PS2 10240      // padded row stride (multiple of 2048 for softmax chunking)
#define NPAD 10112     // fc2 rows padded to 79*128
#define BM 128
#define BN 128
#define BK 32
#define NSLICE 8

typedef __attribute__((ext_vector_type(8))) short bf16x8;
typedef __attribute__((ext_vector_type(4))) float f32x4;

__device__ __forceinline__ float b2f(unsigned short u) {
    union { unsigned int i; float f; } v; v.i = ((unsigned int)u) << 16; return v.f;
}
__device__ __forceinline__ unsigned short f2b(float f) {
    union { float f; unsigned int i; } v; v.f = f;
    unsigned int r = v.i + 0x7fffu + ((v.i >> 16) & 1u);
    return (unsigned short)(r >> 16);
}
__device__ __forceinline__ void glds16(const void* g, void* l) {
    __builtin_amdgcn_global_load_lds(
        (const __attribute__((address_space(1))) void*)g,
        (__attribute__((address_space(3))) void*)l, 16, 0, 0);
}

// Tiled MFMA GEMM: C = A1·W1^T (+ A2·W2^T) + bias1.  128x128 tile, BK=32.
// mode&7: 0 f32 | 1 bf16 relu | 2 f32 slice outF+bz*Bv*Ev | 3 bf16
//         4 LSTM gate epilogue (gate-interleaved weights; outF=c f32, outB=h bf16)
// mode&8: LSTM first step (c_prev = 0)
// mode>>4 (XCD swizzle, 1-D grid): 0 none | 1 fc2(640) | 2 emb1(128) | 3 lstm(64)
__global__ __launch_bounds__(256) void gemm_tile(
    const unsigned short* __restrict__ A1, int lda1,
    const unsigned short* __restrict__ W1, int ldw1,
    const unsigned short* __restrict__ A2, int lda2,
    const unsigned short* __restrict__ W2, int ldw2,
    const float* __restrict__ bias1,
    int Ktot, int kchunk, int Ncols, int mode,
    float* __restrict__ outF, unsigned short* __restrict__ outB, int ldc)
{
    __shared__ unsigned short As[BM * BK];   // 8 KB
    __shared__ unsigned short Bs[BN * BK];   // 8 KB

    int bmode = mode & 7;
    int swz   = mode >> 4;
    int bx, by, bz;
    if (swz == 1) {            // fc2: same-N tiles share bid%8 -> same XCD
        int r = blockIdx.x & 7, q = blockIdx.x >> 3;   // q 0..79
        bx = q & 7; by = r + (q >> 3) * 8; bz = 0;
        if (by >= NPAD / BN) return;
    } else if (swz == 2) {     // emb1: same-K-slice shares bid%8 (8 slices)
        int r = blockIdx.x & 7, q = blockIdx.x >> 3;   // q 0..15
        bz = r; bx = q >> 1; by = q & 1;
    } else if (swz == 3) {     // lstm: transpose so same-N shares bid%8
        bx = blockIdx.x >> 3; by = blockIdx.x & 7; bz = 0;
    } else {
        bx = blockIdx.x; by = blockIdx.y; bz = blockIdx.z;
    }

    int tid  = threadIdx.x;
    int wave = tid >> 6;
    int lane = tid & 63;
    int quad = lane >> 4;
    int l16  = lane & 15;
    int wm = (wave & 1) * 64;
    int wn = (wave >> 1) * 64;
    int m0 = bx * BM;
    int n0 = by * BN;
    int k0 = bz * kchunk;
    int k1 = k0 + kchunk; if (k1 > Ktot) k1 = Ktot;

    f32x4 acc[4][4];
#pragma unroll
    for (int i = 0; i < 4; ++i)
#pragma unroll
        for (int j = 0; j < 4; ++j) acc[i][j] = (f32x4){0.f, 0.f, 0.f, 0.f};

    int c0 = tid, c1 = 256 + tid;
    int row0 = c0 >> 2, row1 = c1 >> 2;
    int g80 = ((c0 & 3) ^ (row0 & 3) ^ ((row0 >> 2) & 3)) * 8;
    int g81 = ((c1 & 3) ^ (row1 & 3) ^ ((row1 >> 2) & 3)) * 8;
    unsigned short* ldsA0 = As + (size_t)(wave * 64) * 8;
    unsigned short* ldsA1 = As + (size_t)(256 + wave * 64) * 8;
    unsigned short* ldsB0 = Bs + (size_t)(wave * 64) * 8;
    unsigned short* ldsB1 = Bs + (size_t)(256 + wave * 64) * 8;

    int nSrc = A2 ? 2 : 1;
    bool first = true;
    for (int s = 0; s < nSrc; ++s) {
        const unsigned short* A = s ? A2 : A1; int lda = s ? lda2 : lda1;
        const unsigned short* W = s ? W2 : W1; int ldw = s ? ldw2 : ldw1;
        for (int k = k0; k < k1; k += BK) {
            if (!first) __syncthreads();
            first = false;
            glds16(A + (size_t)(m0 + row0) * lda + k + g80, ldsA0);
            glds16(A + (size_t)(m0 + row1) * lda + k + g81, ldsA1);
            glds16(W + (size_t)(n0 + row0) * ldw + k + g80, ldsB0);
            glds16(W + (size_t)(n0 + row1) * ldw + k + g81, ldsB1);
            asm volatile("s_waitcnt vmcnt(0)" ::: "memory");
            __syncthreads();

            bf16x8 af[4], bfr[4];
#pragma unroll
            for (int t = 0; t < 4; ++t) {
                int m = wm + t * 16 + l16;
                int ca = quad ^ (m & 3) ^ ((m >> 2) & 3);
                af[t] = *(const bf16x8*)(As + m * 32 + ca * 8);
                int n = wn + t * 16 + l16;
                int cb = quad ^ (n & 3) ^ ((n >> 2) & 3);
                bfr[t] = *(const bf16x8*)(Bs + n * 32 + cb * 8);
            }
#pragma unroll
            for (int i = 0; i < 4; ++i)
#pragma unroll
                for (int j = 0; j < 4; ++j)
                    acc[i][j] = __builtin_amdgcn_mfma_f32_16x16x32_bf16(
                        af[i], bfr[j], acc[i][j], 0, 0, 0);
        }
    }

    // D mapping: col = lane&15, row = quad*4 + reg
    if (bmode == 4) {
        // LSTM gate epilogue: col n = hi*64 + gate*16 + l16 -> e = hi*16+l16
        int hi = (n0 + wn) >> 6;
        int e  = hi * 16 + l16;
        float bi = bias1[(n0 + wn) + 0 * 16 + l16];
        float bf = bias1[(n0 + wn) + 1 * 16 + l16];
        float bg = bias1[(n0 + wn) + 2 * 16 + l16];
        float bo = bias1[(n0 + wn) + 3 * 16 + l16];
#pragma unroll
        for (int i = 0; i < 4; ++i) {
            int mBase = m0 + wm + i * 16 + quad * 4;
#pragma unroll
            for (int r = 0; r < 4; ++r) {
                int m = mBase + r;
                float gi = acc[i][0][r] + bi;
                float gf = acc[i][1][r] + bf;
                float gg = acc[i][2][r] + bg;
                float go = acc[i][3][r] + bo;
                float cp = (mode & 8) ? 0.f : outF[(size_t)m * 256 + e];
                float si = 1.f / (1.f + expf(-gi));
                float sf = 1.f / (1.f + expf(-gf));
                float so = 1.f / (1.f + expf(-go));
                float cn = sf * cp + si * tanhf(gg);
                outF[(size_t)m * 256 + e] = cn;
                outB[(size_t)m * 256 + e] = f2b(so * tanhf(cn));
            }
        }
        return;
    }

#pragma unroll
    for (int j = 0; j < 4; ++j) {
        int n = n0 + wn + j * 16 + l16;
        if (n >= Ncols) continue;
        float bsum = bias1 ? bias1[n] : 0.f;
#pragma unroll
        for (int i = 0; i < 4; ++i) {
            int mBase = m0 + wm + i * 16 + quad * 4;
#pragma unroll
            for (int r = 0; r < 4; ++r) {
                float v = acc[i][j][r] + bsum;
                size_t idx = (size_t)(mBase + r) * ldc + n;
                if (bmode == 0)      outF[idx] = v;
                else if (bmode == 1) outB[idx] = f2b(v > 0.f ? v : 0.f);
                else if (bmode == 2) outF[(size_t)bz * (Bv * Ev) + idx] = v;
                else                 outB[idx] = f2b(v);
            }
        }
    }
}

// merged prep: fc2 conv+pad | w_ih/w_hh gate-interleave | fc1 | bias | embed
// LSTM interleave: out row r <- src row gate*256+e, r = (e&15)|gate<<4|(e>>4)<<6
__global__ void prep_k(const float* __restrict__ w_ih,
                       const float* __restrict__ w_hh,
                       const float* __restrict__ fc1_w,
                       const float* __restrict__ fc2_w,
                       const float* __restrict__ b_ih,
                       const float* __restrict__ b_hh,
                       const int* __restrict__ bodys,
                       const float* __restrict__ emb_w,
                       unsigned short* __restrict__ w_ih_b,
                       unsigned short* __restrict__ w_hh_b,
                       unsigned short* __restrict__ fc1_w_b,
                       unsigned short* __restrict__ fc2_w_b,
                       float* __restrict__ biasC,
                       unsigned short* __restrict__ x)
{
    int b = blockIdx.x, t = threadIdx.x;
    if (b < 1264) {                       // fc2: NPAD*Ev = 1264*2048
#pragma unroll
        for (int j = 0; j < 8; ++j) {
            int i = b * 2048 + j * 256 + t;
            fc2_w_b[i] = (i < NP1 * Ev) ? f2b(fc2_w[i]) : (unsigned short)0;
        }
    } else if (b < 1520) {                // w_ih / w_hh interleaved: 256 blocks
        int bb = b - 1264;                // 0..255 -> 4 rows each
        const float* src = (bb < 128) ? w_ih : w_hh;
        unsigned short* dst = (bb < 128) ? w_ih_b : w_hh_b;
        int rb = (bb & 127) * 8;
#pragma unroll
        for (int j = 0; j < 8; ++j) {
            int r = rb + j;
            int gate = (r >> 4) & 3;
            int e = (r & 15) | ((r >> 6) << 4);
            dst[(size_t)r * 256 + t] = f2b(src[(size_t)(gate * 256 + e) * 256 + t]);
        }
    } else if (b < 1584) {                // fc1: 64*2048 = 131072
        int base = (b - 1520) * 2048;
#pragma unroll
        for (int j = 0; j < 8; ++j) {
            int i = base + j * 256 + t;
            fc1_w_b[i] = f2b(fc1_w[i]);
        }
    } else if (b < 1585) {                // bias combine (interleaved)
#pragma unroll
        for (int j = 0; j < 4; ++j) {
            int r = j * 256 + t;
            int gate = (r >> 4) & 3;
            int e = (r & 15) | ((r >> 6) << 4);
            biasC[r] = b_ih[gate * 256 + e] + b_hh[gate * 256 + e];
        }
    } else {                              // embed gather: 1024 blocks, 8 rows each
        int bb = b - 1585;
#pragma unroll
        for (int j = 0; j < 8; ++j) {
            int row = bb * 8 + j;
            x[(size_t)row * Ev + t] = f2b(emb_w[(size_t)bodys[row] * Ev + t]);
        }
    }
}

// coalesced 32x32 tiled transpose: embT[e][k] = bf16(emb_w[k][e]), pad zeroed
__global__ void transpose_emb(const float* __restrict__ emb_w,
                              unsigned short* __restrict__ embT)
{
    __shared__ float tile[32][33];
    int kt = blockIdx.x * 32, et = blockIdx.y * 32;
    int tx = threadIdx.x & 31, ty = threadIdx.x >> 5;
#pragma unroll
    for (int r = ty; r < 32; r += 8) {
        int k = kt + r;
        tile[r][tx] = (k < Rv) ? emb_w[(size_t)k * Ev + et + tx] : 0.f;
    }
    __syncthreads();
#pragma unroll
    for (int r = ty; r < 32; r += 8) {
        embT[(size_t)(et + r) * PS2 + kt + tx] = f2b(tile[tx][r]);
    }
}

// single-pass register softmax over bf16 logits (stride PS2, valid < NP1)
__global__ __launch_bounds__(256) void softmax_k(
    const unsigned short* __restrict__ probB,
    unsigned short* __restrict__ sfA,
    float* __restrict__ sfLast)
{
    int b = blockIdx.x, tid = threadIdx.x;
    int wave = tid >> 6, lane = tid & 63;
    __shared__ float redm[4], reds[4];
    const unsigned short* pr = probB + (size_t)b * PS2;

    bf16x8 pv[5];
#pragma unroll
    for (int c = 0; c < 5; ++c)
        pv[c] = *(const bf16x8*)(pr + c * 2048 + tid * 8);

    float m = -1e30f;
#pragma unroll
    for (int c = 0; c < 5; ++c)
#pragma unroll
        for (int j = 0; j < 8; ++j) {
            int k = c * 2048 + tid * 8 + j;
            if (k < NP1) m = fmaxf(m, b2f((unsigned short)pv[c][j]));
        }
    for (int off = 32; off; off >>= 1) m = fmaxf(m, __shfl_down(m, off));
    if (lane == 0) redm[wave] = m;
    __syncthreads();
    m = fmaxf(fmaxf(redm[0], redm[1]), fmaxf(redm[2], redm[3]));

    float e[40];
    float s = 0.f;
#pragma unroll
    for (int c = 0; c < 5; ++c)
#pragma unroll
        for (int j = 0; j < 8; ++j) {
            int k = c * 2048 + tid * 8 + j;
            float v = (k < NP1) ? expf(b2f((unsigned short)pv[c][j]) - m) : 0.f;
            e[c * 8 + j] = v;
            s += v;
        }
    for (int off = 32; off; off >>= 1) s += __shfl_down(s, off);
    if (lane == 0) reds[wave] = s;
    __syncthreads();
    s = reds[0] + reds[1] + reds[2] + reds[3];
    float inv = 1.f / s;

    unsigned short* sr = sfA + (size_t)b * PS2;
#pragma unroll
    for (int c = 0; c < 5; ++c) {
        bf16x8 w;
#pragma unroll
        for (int j = 0; j < 8; ++j) {
            int k = c * 2048 + tid * 8 + j;
            float v = (k < Rv) ? e[c * 8 + j] * inv : 0.f;
            w[j] = (short)f2b(v);
            if (k == Rv) sfLast[b] = e[c * 8 + j] * inv;
        }
        *(bf16x8*)(sr + c * 2048 + tid * 8) = w;
    }
}

__global__ void concat0(const int* __restrict__ bodys,
                        const float* __restrict__ emb_w,
                        unsigned short* __restrict__ embc)
{
    int b = blockIdx.x, e = threadIdx.x;
    embc[(size_t)b * 512 + e]       = f2b(emb_w[(size_t)bodys[b * Lv + 0] * Ev + e]);
    embc[(size_t)b * 512 + 256 + e] = f2b(emb_w[(size_t)bodys[b * Lv + 1] * Ev + e]);
}

// sum NSLICE split-K partials + sfLast*h -> embc bf16; last iter: also f32 out
__global__ void finalize_emb(const float* __restrict__ emb1p,
                             const float* __restrict__ sfLast,
                             const unsigned short* __restrict__ h_i,
                             const float* __restrict__ emb_row,
                             unsigned short* __restrict__ embc,
                             float* __restrict__ outTail)   // null unless last
{
    int b = blockIdx.x, e = threadIdx.x;
    float v = 0.f;
#pragma unroll
    for (int z = 0; z < NSLICE; ++z)
        v += emb1p[(size_t)z * (Bv * Ev) + (size_t)b * Ev + e];
    v += sfLast[b] * b2f(h_i[(size_t)b * Ev + e]);
    float w = emb_row[e];
    embc[(size_t)b * 512 + e]       = f2b(v);
    embc[(size_t)b * 512 + 256 + e] = f2b(w);
    if (outTail) {
        outTail[(size_t)b * 512 + e]       = v;
        outTail[(size_t)b * 512 + 256 + e] = w;
    }
}

extern "C" void kernel_launch(void* const* d_in, const int* in_sizes, int n_in,
                              void* d_out, int out_size, void* d_ws, size_t ws_size,
                              hipStream_t stream)
{
    const int*   bodys = (const int*)d_in[0];
    const float* emb_w = (const float*)d_in[1];
    const float* w_ih  = (const float*)d_in[2];
    const float* w_hh  = (const float*)d_in[3];
    const float* b_ih  = (const float*)d_in[4];
    const float* b_hh  = (const float*)d_in[5];
    const float* fc1_w = (const float*)d_in[6];
    const float* fc1_b = (const float*)d_in[7];
    const float* fc2_w = (const float*)d_in[8];
    const float* fc2_b = (const float*)d_in[9];
    float* out = (float*)d_out;

    char* ws = (char*)d_ws;
    size_t off = 0;
    auto alloc = [&](size_t bytes) -> void* {
        void* p = ws + off;
        off += (bytes + 255) & ~(size_t)255;
        return p;
    };
    unsigned short* x       = (unsigned short*)alloc((size_t)Bv * Lv * Ev * 2);
    unsigned short* hs      = (unsigned short*)alloc((size_t)Lv * Bv * Ev * 2);
    float*          cbuf    = (float*)alloc((size_t)Bv * Ev * 4);
    unsigned short* embT    = (unsigned short*)alloc((size_t)Ev * PS2 * 2);
    unsigned short* sfA     = (unsigned short*)alloc((size_t)Bv * PS2 * 2);
    float*          sfLast  = (float*)alloc((size_t)Bv * 4);
    unsigned short* probB   = (unsigned short*)alloc((size_t)Bv * PS2 * 2);
    float*          emb1p   = (float*)alloc((size_t)NSLICE * Bv * Ev * 4);
    unsigned short* embc    = (unsigned short*)alloc((size_t)Bv * 512 * 2);
    unsigned short* hiddenA = (unsigned short*)alloc((size_t)Bv * Ev * 2);
    unsigned short* w_ih_b  = (unsigned short*)alloc((size_t)1024 * Ev * 2);
    unsigned short* w_hh_b  = (unsigned short*)alloc((size_t)1024 * Ev * 2);
    float*          biasC   = (float*)alloc((size_t)1024 * 4);
    unsigned short* fc1_w_b = (unsigned short*)alloc((size_t)Ev * 512 * 2);
    unsigned short* fc2_w_b = (unsigned short*)alloc((size_t)NPAD * Ev * 2);
    (void)ws_size; (void)in_sizes; (void)n_in; (void)out_size;

    prep_k<<<2609, 256, 0, stream>>>(w_ih, w_hh, fc1_w, fc2_w, b_ih, b_hh,
                                     bodys, emb_w,
                                     w_ih_b, w_hh_b, fc1_w_b, fc2_w_b, biasC, x);
    transpose_emb<<<dim3(PS2 / 32, Ev / 32), 256, 0, stream>>>(emb_w, embT);

    // LSTM: 8 steps, fused gate epilogue (mode 4, swz 3)
    for (int t = 0; t < Lv; ++t) {
        gemm_tile<<<64, 256, 0, stream>>>(
            x + t * Ev, Lv * Ev, w_ih_b, Ev,
            (t == 0) ? nullptr : (hs + (size_t)(t - 1) * Bv * Ev), Ev, w_hh_b, Ev,
            biasC,
            Ev, Ev, 1024, 4 | (t == 0 ? 8 : 0) | (3 << 4),
            cbuf, hs + (size_t)t * Bv * Ev, 1024);
    }

    for (int i = 0; i < 7; ++i) {
        if (i == 0) {
            concat0<<<Bv, 256, 0, stream>>>(bodys, emb_w, embc);
        } else {
            // emb_1: sfA(1024 x PS2) @ embT^T -> 8 f32 slices (swz=2)
            gemm_tile<<<128, 256, 0, stream>>>(
                sfA, PS2, embT, PS2, nullptr, 0, nullptr, 0,
                nullptr,
                PS2, PS2 / NSLICE, Ev, 2 | (2 << 4),
                emb1p, nullptr, Ev);
            finalize_emb<<<Bv, 256, 0, stream>>>(
                emb1p, sfLast, hs + (size_t)i * Bv * Ev,
                emb_w + (size_t)(i + 1) * Ev, embc,
                (i == 6) ? (out + (size_t)Bv * NP1) : nullptr);
        }
        // fc1: hidden = relu(embc(1024x512) @ fc1_w^T) -> bf16
        gemm_tile<<<dim3(8, 2, 1), 256, 0, stream>>>(
            embc, 512, fc1_w_b, 512, nullptr, 0, nullptr, 0,
            fc1_b,
            512, 512, Ev, 1,
            nullptr, hiddenA, Ev);
        // fc2: prob = hidden(1024x256) @ fc2_w^T (swz=1)
        if (i < 6) {
            gemm_tile<<<640, 256, 0, stream>>>(
                hiddenA, Ev, fc2_w_b, Ev, nullptr, 0, nullptr, 0,
                fc2_b,
                Ev, Ev, NP1, 3 | (1 << 4),
                nullptr, probB, PS2);
            softmax_k<<<Bv, 256, 0, stream>>>(probB, sfA, sfLast);
        } else {
            gemm_tile<<<640, 256, 0, stream>>>(
                hiddenA, Ev, fc2_w_b, Ev, nullptr, 0, nullptr, 0,
                fc2_b,
                Ev, Ev, NP1, 0 | (1 << 4),
                out, nullptr, NP1);
        }
    }
}

// Round 8
// 615.385 us; speedup vs baseline: 1.2582x; 1.2582x over previous
//
#include <hip/hip_runtime.h>

#define Bv 1024
#define Ev 256
#define Lv 8
#define Rv 10000
#define NP1 10001
#define PS2 10240      // padded row stride (multiple of 2048 for softmax chunking)
#define NPAD 10112     // fc2 rows padded to 79*128
#define BM 128
#define BN 128
#define BK 32
#define NSLICE 16

typedef __attribute__((ext_vector_type(8))) short bf16x8;
typedef __attribute__((ext_vector_type(4))) float f32x4;

__device__ __forceinline__ float b2f(unsigned short u) {
    union { unsigned int i; float f; } v; v.i = ((unsigned int)u) << 16; return v.f;
}
__device__ __forceinline__ unsigned short f2b(float f) {
    union { float f; unsigned int i; } v; v.f = f;
    unsigned int r = v.i + 0x7fffu + ((v.i >> 16) & 1u);
    return (unsigned short)(r >> 16);
}
__device__ __forceinline__ void glds16(const void* g, void* l) {
    __builtin_amdgcn_global_load_lds(
        (const __attribute__((address_space(1))) void*)g,
        (__attribute__((address_space(3))) void*)l, 16, 0, 0);
}

// ---------- 128x128 tile GEMM (fc2 / emb1) ----------
// mode&7: 0 f32 | 2 f32 slice outF+bz*Bv*Ev | 3 bf16
// mode>>4 (XCD swizzle, 1-D grid): 1 fc2(640) | 2 emb1(256, 16 slices)
__global__ __launch_bounds__(256) void gemm_tile(
    const unsigned short* __restrict__ A1, int lda1,
    const unsigned short* __restrict__ W1, int ldw1,
    const float* __restrict__ bias1,
    int Ktot, int kchunk, int Ncols, int mode,
    float* __restrict__ outF, unsigned short* __restrict__ outB, int ldc)
{
    __shared__ unsigned short As[BM * BK];   // 8 KB
    __shared__ unsigned short Bs[BN * BK];   // 8 KB

    int bmode = mode & 7;
    int swz   = mode >> 4;
    int bx, by, bz;
    if (swz == 1) {            // fc2: same-N tiles share bid%8 -> same XCD
        int r = blockIdx.x & 7, q = blockIdx.x >> 3;   // q 0..79
        bx = q & 7; by = r + (q >> 3) * 8; bz = 0;
        if (by >= NPAD / BN) return;
    } else if (swz == 2) {     // emb1: same-K-slice shares bid%8 (16 slices)
        int r = blockIdx.x & 7, q = blockIdx.x >> 3;   // q 0..31
        bz = r + (q >> 4) * 8; bx = (q & 15) >> 1; by = q & 1;
    } else {
        bx = blockIdx.x; by = blockIdx.y; bz = blockIdx.z;
    }

    int tid  = threadIdx.x;
    int wave = tid >> 6;
    int lane = tid & 63;
    int quad = lane >> 4;
    int l16  = lane & 15;
    int wm = (wave & 1) * 64;
    int wn = (wave >> 1) * 64;
    int m0 = bx * BM;
    int n0 = by * BN;
    int k0 = bz * kchunk;
    int k1 = k0 + kchunk; if (k1 > Ktot) k1 = Ktot;

    f32x4 acc[4][4];
#pragma unroll
    for (int i = 0; i < 4; ++i)
#pragma unroll
        for (int j = 0; j < 4; ++j) acc[i][j] = (f32x4){0.f, 0.f, 0.f, 0.f};

    int c0 = tid, c1 = 256 + tid;
    int row0 = c0 >> 2, row1 = c1 >> 2;
    int g80 = ((c0 & 3) ^ (row0 & 3) ^ ((row0 >> 2) & 3)) * 8;
    int g81 = ((c1 & 3) ^ (row1 & 3) ^ ((row1 >> 2) & 3)) * 8;
    unsigned short* ldsA0 = As + (size_t)(wave * 64) * 8;
    unsigned short* ldsA1 = As + (size_t)(256 + wave * 64) * 8;
    unsigned short* ldsB0 = Bs + (size_t)(wave * 64) * 8;
    unsigned short* ldsB1 = Bs + (size_t)(256 + wave * 64) * 8;

    bool first = true;
    for (int k = k0; k < k1; k += BK) {
        if (!first) __syncthreads();
        first = false;
        glds16(A1 + (size_t)(m0 + row0) * lda1 + k + g80, ldsA0);
        glds16(A1 + (size_t)(m0 + row1) * lda1 + k + g81, ldsA1);
        glds16(W1 + (size_t)(n0 + row0) * ldw1 + k + g80, ldsB0);
        glds16(W1 + (size_t)(n0 + row1) * ldw1 + k + g81, ldsB1);
        asm volatile("s_waitcnt vmcnt(0)" ::: "memory");
        __syncthreads();

        bf16x8 af[4], bfr[4];
#pragma unroll
        for (int t = 0; t < 4; ++t) {
            int m = wm + t * 16 + l16;
            int ca = quad ^ (m & 3) ^ ((m >> 2) & 3);
            af[t] = *(const bf16x8*)(As + m * 32 + ca * 8);
            int n = wn + t * 16 + l16;
            int cb = quad ^ (n & 3) ^ ((n >> 2) & 3);
            bfr[t] = *(const bf16x8*)(Bs + n * 32 + cb * 8);
        }
#pragma unroll
        for (int i = 0; i < 4; ++i)
#pragma unroll
            for (int j = 0; j < 4; ++j)
                acc[i][j] = __builtin_amdgcn_mfma_f32_16x16x32_bf16(
                    af[i], bfr[j], acc[i][j], 0, 0, 0);
    }

    // D mapping: col = lane&15, row = quad*4 + reg
#pragma unroll
    for (int j = 0; j < 4; ++j) {
        int n = n0 + wn + j * 16 + l16;
        if (n >= Ncols) continue;
        float bsum = bias1 ? bias1[n] : 0.f;
#pragma unroll
        for (int i = 0; i < 4; ++i) {
            int mBase = m0 + wm + i * 16 + quad * 4;
#pragma unroll
            for (int r = 0; r < 4; ++r) {
                float v = acc[i][j][r] + bsum;
                size_t idx = (size_t)(mBase + r) * ldc + n;
                if (bmode == 0)      outF[idx] = v;
                else if (bmode == 2) outF[(size_t)bz * (Bv * Ev) + idx] = v;
                else                 outB[idx] = f2b(v);
            }
        }
    }
}

// ---------- 64x64 tile GEMM (LSTM / fc1) ----------
// 4 waves stacked in M; wave w: rows [w*16, w*16+16), all 64 cols (j=0..3).
// mode&7: 1 bf16 relu | 4 LSTM gate epilogue (outF=c f32, outB=h bf16, ld 256)
// mode&8: LSTM first step. Grid 1-D: by = bid & (2^shift-1), bx = bid >> shift.
__global__ __launch_bounds__(256) void gemm64(
    const unsigned short* __restrict__ A1, int lda1,
    const unsigned short* __restrict__ W1, int ldw1,
    const unsigned short* __restrict__ A2, int lda2,
    const unsigned short* __restrict__ W2, int ldw2,
    const float* __restrict__ bias1,
    int Ktot, int Ncols, int mode,
    float* __restrict__ outF, unsigned short* __restrict__ outB,
    int ldc, int nshift)
{
    __shared__ unsigned short As[64 * 32];   // 4 KB
    __shared__ unsigned short Bs[64 * 32];   // 4 KB

    int bmode = mode & 7;
    int bx = blockIdx.x >> nshift;
    int by = blockIdx.x & ((1 << nshift) - 1);
    int tid  = threadIdx.x;
    int wave = tid >> 6;
    int lane = tid & 63;
    int quad = lane >> 4;
    int l16  = lane & 15;
    int m0 = bx * 64;
    int n0 = by * 64;

    f32x4 acc[4];
#pragma unroll
    for (int j = 0; j < 4; ++j) acc[j] = (f32x4){0.f, 0.f, 0.f, 0.f};

    int row = tid >> 2;
    int g8  = ((tid & 3) ^ (row & 3) ^ ((row >> 2) & 3)) * 8;
    unsigned short* ldsA = As + wave * 512;
    unsigned short* ldsB = Bs + wave * 512;

    int nSrc = A2 ? 2 : 1;
    bool first = true;
    for (int s = 0; s < nSrc; ++s) {
        const unsigned short* A = s ? A2 : A1; int lda = s ? lda2 : lda1;
        const unsigned short* W = s ? W2 : W1; int ldw = s ? ldw2 : ldw1;
        for (int k = 0; k < Ktot; k += 32) {
            if (!first) __syncthreads();
            first = false;
            glds16(A + (size_t)(m0 + row) * lda + k + g8, ldsA);
            glds16(W + (size_t)(n0 + row) * ldw + k + g8, ldsB);
            asm volatile("s_waitcnt vmcnt(0)" ::: "memory");
            __syncthreads();

            int ml = wave * 16 + l16;
            int ca = quad ^ (ml & 3) ^ ((ml >> 2) & 3);
            bf16x8 a = *(const bf16x8*)(As + ml * 32 + ca * 8);
#pragma unroll
            for (int j = 0; j < 4; ++j) {
                int nl = j * 16 + l16;
                int cb = quad ^ (nl & 3) ^ ((nl >> 2) & 3);
                bf16x8 b = *(const bf16x8*)(Bs + nl * 32 + cb * 8);
                acc[j] = __builtin_amdgcn_mfma_f32_16x16x32_bf16(a, b, acc[j], 0, 0, 0);
            }
        }
    }

    if (bmode == 4) {
        // gate-interleaved cols: n = by*64 + gate*16 + l16 -> e = by*16 + l16
        int e  = by * 16 + l16;
        float bi = bias1[n0 + l16];
        float bf_ = bias1[n0 + 16 + l16];
        float bg = bias1[n0 + 32 + l16];
        float bo = bias1[n0 + 48 + l16];
#pragma unroll
        for (int r = 0; r < 4; ++r) {
            int m = m0 + wave * 16 + quad * 4 + r;
            float gi = acc[0][r] + bi;
            float gf = acc[1][r] + bf_;
            float gg = acc[2][r] + bg;
            float go = acc[3][r] + bo;
            float cp = (mode & 8) ? 0.f : outF[(size_t)m * 256 + e];
            float si = 1.f / (1.f + expf(-gi));
            float sf = 1.f / (1.f + expf(-gf));
            float so = 1.f / (1.f + expf(-go));
            float cn = sf * cp + si * tanhf(gg);
            outF[(size_t)m * 256 + e] = cn;
            outB[(size_t)m * 256 + e] = f2b(so * tanhf(cn));
        }
        return;
    }

#pragma unroll
    for (int j = 0; j < 4; ++j) {
        int n = n0 + j * 16 + l16;
        if (n >= Ncols) continue;
        float bsum = bias1 ? bias1[n] : 0.f;
#pragma unroll
        for (int r = 0; r < 4; ++r) {
            int m = m0 + wave * 16 + quad * 4 + r;
            float v = acc[j][r] + bsum;
            if (bmode == 1) outB[(size_t)m * ldc + n] = f2b(v > 0.f ? v : 0.f);
            else            outB[(size_t)m * ldc + n] = f2b(v);
        }
    }
}

// merged prep: fc2 conv+pad | w_ih/w_hh gate-interleave | fc1 | bias | embed
// LSTM interleave: out row r <- src row gate*256+e, r = (e&15)|gate<<4|(e>>4)<<6
__global__ void prep_k(const float* __restrict__ w_ih,
                       const float* __restrict__ w_hh,
                       const float* __restrict__ fc1_w,
                       const float* __restrict__ fc2_w,
                       const float* __restrict__ b_ih,
                       const float* __restrict__ b_hh,
                       const int* __restrict__ bodys,
                       const float* __restrict__ emb_w,
                       unsigned short* __restrict__ w_ih_b,
                       unsigned short* __restrict__ w_hh_b,
                       unsigned short* __restrict__ fc1_w_b,
                       unsigned short* __restrict__ fc2_w_b,
                       float* __restrict__ biasC,
                       unsigned short* __restrict__ x)
{
    int b = blockIdx.x, t = threadIdx.x;
    if (b < 1264) {                       // fc2: NPAD*Ev = 1264*2048
#pragma unroll
        for (int j = 0; j < 8; ++j) {
            int i = b * 2048 + j * 256 + t;
            fc2_w_b[i] = (i < NP1 * Ev) ? f2b(fc2_w[i]) : (unsigned short)0;
        }
    } else if (b < 1520) {                // w_ih / w_hh interleaved
        int bb = b - 1264;                // 0..255
        const float* src = (bb < 128) ? w_ih : w_hh;
        unsigned short* dst = (bb < 128) ? w_ih_b : w_hh_b;
        int rb = (bb & 127) * 8;
#pragma unroll
        for (int j = 0; j < 8; ++j) {
            int r = rb + j;
            int gate = (r >> 4) & 3;
            int e = (r & 15) | ((r >> 6) << 4);
            dst[(size_t)r * 256 + t] = f2b(src[(size_t)(gate * 256 + e) * 256 + t]);
        }
    } else if (b < 1584) {                // fc1: 64*2048 = 131072
        int base = (b - 1520) * 2048;
#pragma unroll
        for (int j = 0; j < 8; ++j) {
            int i = base + j * 256 + t;
            fc1_w_b[i] = f2b(fc1_w[i]);
        }
    } else if (b < 1585) {                // bias combine (interleaved)
#pragma unroll
        for (int j = 0; j < 4; ++j) {
            int r = j * 256 + t;
            int gate = (r >> 4) & 3;
            int e = (r & 15) | ((r >> 6) << 4);
            biasC[r] = b_ih[gate * 256 + e] + b_hh[gate * 256 + e];
        }
    } else {                              // embed gather: 1024 blocks, 8 rows each
        int bb = b - 1585;
#pragma unroll
        for (int j = 0; j < 8; ++j) {
            int row = bb * 8 + j;
            x[(size_t)row * Ev + t] = f2b(emb_w[(size_t)bodys[row] * Ev + t]);
        }
    }
}

// coalesced 32x32 tiled transpose: embT[e][k] = bf16(emb_w[k][e]), pad zeroed
__global__ void transpose_emb(const float* __restrict__ emb_w,
                              unsigned short* __restrict__ embT)
{
    __shared__ float tile[32][33];
    int kt = blockIdx.x * 32, et = blockIdx.y * 32;
    int tx = threadIdx.x & 31, ty = threadIdx.x >> 5;
#pragma unroll
    for (int r = ty; r < 32; r += 8) {
        int k = kt + r;
        tile[r][tx] = (k < Rv) ? emb_w[(size_t)k * Ev + et + tx] : 0.f;
    }
    __syncthreads();
#pragma unroll
    for (int r = ty; r < 32; r += 8) {
        embT[(size_t)(et + r) * PS2 + kt + tx] = f2b(tile[tx][r]);
    }
}

// single-pass register softmax over bf16 logits (stride PS2, valid < NP1)
__global__ __launch_bounds__(256) void softmax_k(
    const unsigned short* __restrict__ probB,
    unsigned short* __restrict__ sfA,
    float* __restrict__ sfLast)
{
    int b = blockIdx.x, tid = threadIdx.x;
    int wave = tid >> 6, lane = tid & 63;
    __shared__ float redm[4], reds[4];
    const unsigned short* pr = probB + (size_t)b * PS2;

    bf16x8 pv[5];
#pragma unroll
    for (int c = 0; c < 5; ++c)
        pv[c] = *(const bf16x8*)(pr + c * 2048 + tid * 8);

    float m = -1e30f;
#pragma unroll
    for (int c = 0; c < 5; ++c)
#pragma unroll
        for (int j = 0; j < 8; ++j) {
            int k = c * 2048 + tid * 8 + j;
            if (k < NP1) m = fmaxf(m, b2f((unsigned short)pv[c][j]));
        }
    for (int off = 32; off; off >>= 1) m = fmaxf(m, __shfl_down(m, off));
    if (lane == 0) redm[wave] = m;
    __syncthreads();
    m = fmaxf(fmaxf(redm[0], redm[1]), fmaxf(redm[2], redm[3]));

    float e[40];
    float s = 0.f;
#pragma unroll
    for (int c = 0; c < 5; ++c)
#pragma unroll
        for (int j = 0; j < 8; ++j) {
            int k = c * 2048 + tid * 8 + j;
            float v = (k < NP1) ? expf(b2f((unsigned short)pv[c][j]) - m) : 0.f;
            e[c * 8 + j] = v;
            s += v;
        }
    for (int off = 32; off; off >>= 1) s += __shfl_down(s, off);
    if (lane == 0) reds[wave] = s;
    __syncthreads();
    s = reds[0] + reds[1] + reds[2] + reds[3];
    float inv = 1.f / s;

    unsigned short* sr = sfA + (size_t)b * PS2;
#pragma unroll
    for (int c = 0; c < 5; ++c) {
        bf16x8 w;
#pragma unroll
        for (int j = 0; j < 8; ++j) {
            int k = c * 2048 + tid * 8 + j;
            float v = (k < Rv) ? e[c * 8 + j] * inv : 0.f;
            w[j] = (short)f2b(v);
            if (k == Rv) sfLast[b] = e[c * 8 + j] * inv;
        }
        *(bf16x8*)(sr + c * 2048 + tid * 8) = w;
    }
}

__global__ void concat0(const int* __restrict__ bodys,
                        const float* __restrict__ emb_w,
                        unsigned short* __restrict__ embc)
{
    int b = blockIdx.x, e = threadIdx.x;
    embc[(size_t)b * 512 + e]       = f2b(emb_w[(size_t)bodys[b * Lv + 0] * Ev + e]);
    embc[(size_t)b * 512 + 256 + e] = f2b(emb_w[(size_t)bodys[b * Lv + 1] * Ev + e]);
}

// sum NSLICE split-K partials + sfLast*h -> embc bf16; last iter: also f32 out
__global__ void finalize_emb(const float* __restrict__ emb1p,
                             const float* __restrict__ sfLast,
                             const unsigned short* __restrict__ h_i,
                             const float* __restrict__ emb_row,
                             unsigned short* __restrict__ embc,
                             float* __restrict__ outTail)   // null unless last
{
    int b = blockIdx.x, e = threadIdx.x;
    float v = 0.f;
#pragma unroll
    for (int z = 0; z < NSLICE; ++z)
        v += emb1p[(size_t)z * (Bv * Ev) + (size_t)b * Ev + e];
    v += sfLast[b] * b2f(h_i[(size_t)b * Ev + e]);
    float w = emb_row[e];
    embc[(size_t)b * 512 + e]       = f2b(v);
    embc[(size_t)b * 512 + 256 + e] = f2b(w);
    if (outTail) {
        outTail[(size_t)b * 512 + e]       = v;
        outTail[(size_t)b * 512 + 256 + e] = w;
    }
}

extern "C" void kernel_launch(void* const* d_in, const int* in_sizes, int n_in,
                              void* d_out, int out_size, void* d_ws, size_t ws_size,
                              hipStream_t stream)
{
    const int*   bodys = (const int*)d_in[0];
    const float* emb_w = (const float*)d_in[1];
    const float* w_ih  = (const float*)d_in[2];
    const float* w_hh  = (const float*)d_in[3];
    const float* b_ih  = (const float*)d_in[4];
    const float* b_hh  = (const float*)d_in[5];
    const float* fc1_w = (const float*)d_in[6];
    const float* fc1_b = (const float*)d_in[7];
    const float* fc2_w = (const float*)d_in[8];
    const float* fc2_b = (const float*)d_in[9];
    float* out = (float*)d_out;

    char* ws = (char*)d_ws;
    size_t off = 0;
    auto alloc = [&](size_t bytes) -> void* {
        void* p = ws + off;
        off += (bytes + 255) & ~(size_t)255;
        return p;
    };
    unsigned short* x       = (unsigned short*)alloc((size_t)Bv * Lv * Ev * 2);
    unsigned short* hs      = (unsigned short*)alloc((size_t)Lv * Bv * Ev * 2);
    float*          cbuf    = (float*)alloc((size_t)Bv * Ev * 4);
    unsigned short* embT    = (unsigned short*)alloc((size_t)Ev * PS2 * 2);
    unsigned short* sfA     = (unsigned short*)alloc((size_t)Bv * PS2 * 2);
    float*          sfLast  = (float*)alloc((size_t)Bv * 4);
    unsigned short* probB   = (unsigned short*)alloc((size_t)Bv * PS2 * 2);
    float*          emb1p   = (float*)alloc((size_t)NSLICE * Bv * Ev * 4);
    unsigned short* embc    = (unsigned short*)alloc((size_t)Bv * 512 * 2);
    unsigned short* hiddenA = (unsigned short*)alloc((size_t)Bv * Ev * 2);
    unsigned short* w_ih_b  = (unsigned short*)alloc((size_t)1024 * Ev * 2);
    unsigned short* w_hh_b  = (unsigned short*)alloc((size_t)1024 * Ev * 2);
    float*          biasC   = (float*)alloc((size_t)1024 * 4);
    unsigned short* fc1_w_b = (unsigned short*)alloc((size_t)Ev * 512 * 2);
    unsigned short* fc2_w_b = (unsigned short*)alloc((size_t)NPAD * Ev * 2);
    (void)ws_size; (void)in_sizes; (void)n_in; (void)out_size;

    prep_k<<<2609, 256, 0, stream>>>(w_ih, w_hh, fc1_w, fc2_w, b_ih, b_hh,
                                     bodys, emb_w,
                                     w_ih_b, w_hh_b, fc1_w_b, fc2_w_b, biasC, x);
    transpose_emb<<<dim3(PS2 / 32, Ev / 32), 256, 0, stream>>>(emb_w, embT);

    // LSTM: 8 steps, 64x64 tiles (256 blocks), fused gate epilogue
    for (int t = 0; t < Lv; ++t) {
        gemm64<<<256, 256, 0, stream>>>(
            x + t * Ev, Lv * Ev, w_ih_b, Ev,
            (t == 0) ? nullptr : (hs + (size_t)(t - 1) * Bv * Ev), Ev, w_hh_b, Ev,
            biasC,
            Ev, 1024, 4 | (t == 0 ? 8 : 0),
            cbuf, hs + (size_t)t * Bv * Ev, 1024, 4);
    }

    for (int i = 0; i < 7; ++i) {
        if (i == 0) {
            concat0<<<Bv, 256, 0, stream>>>(bodys, emb_w, embc);
        } else {
            // emb_1: sfA(1024 x PS2) @ embT^T -> 16 f32 slices (swz=2)
            gemm_tile<<<256, 256, 0, stream>>>(
                sfA, PS2, embT, PS2,
                nullptr,
                PS2, PS2 / NSLICE, Ev, 2 | (2 << 4),
                emb1p, nullptr, Ev);
            finalize_emb<<<Bv, 256, 0, stream>>>(
                emb1p, sfLast, hs + (size_t)i * Bv * Ev,
                emb_w + (size_t)(i + 1) * Ev, embc,
                (i == 6) ? (out + (size_t)Bv * NP1) : nullptr);
        }
        // fc1: hidden = relu(embc(1024x512) @ fc1_w^T) -> bf16, 64 blocks
        gemm64<<<64, 256, 0, stream>>>(
            embc, 512, fc1_w_b, 512, nullptr, 0, nullptr, 0,
            fc1_b,
            512, 256, 1,
            nullptr, hiddenA, 256, 2);
        // fc2: prob = hidden(1024x256) @ fc2_w^T (swz=1)
        if (i < 6) {
            gemm_tile<<<640, 256, 0, stream>>>(
                hiddenA, Ev, fc2_w_b, Ev,
                fc2_b,
                Ev, Ev, NP1, 3 | (1 << 4),
                nullptr, probB, PS2);
            softmax_k<<<Bv, 256, 0, stream>>>(probB, sfA, sfLast);
        } else {
            gemm_tile<<<640, 256, 0, stream>>>(
                hiddenA, Ev, fc2_w_b, Ev,
                fc2_b,
                Ev, Ev, NP1, 0 | (1 << 4),
                out, nullptr, NP1);
        }
    }
}